// Round 1
// 927.540 us; speedup vs baseline: 3.8263x; 3.8263x over previous
//
#include <hip/hip_runtime.h>

// Swin shifted-window attention, B=1, C=96, H=W=512, ws=8, heads=6, shift=4.
// All inputs/outputs fp32 (dtype contract from prior session).
//
// v2 structure: no weight staging in LDS. Each barrier-separated phase uses
// its own thread->work map:
//   QKV  : token = lane, dims = wave*4..+3  -> weight rows wave-uniform, so
//          weights come in as scalar (s_load) float4s from L2/K$.
//   attn : row r = wave*16 + (lane>>2), col-group cg = lane&3 -> 4-lane
//          shuffle softmax; k/v LDS reads are wave-broadcast.
//   proj : token = lane, out-cols = wave*24..+23 -> scalar float2 weights.
// y round-trips through the xt LDS region (dead after last QKV).
// LDS 44.8KB -> 3 blocks/CU (12 waves) vs prior 61.4KB/2 blocks.

namespace {
constexpr int kH = 512, kW = 512, kC = 96;
constexpr int kWS = 8, kN = 64, kNH = 6;
constexpr int kShift = 4;
constexpr int kHW = kH * kW;   // 262144
constexpr int kWC = kW * kC;   // 49152

constexpr int XT_STRIDE = 97;                       // xt / yS [64][97]
constexpr int XT_OFF = 0;
constexpr int QKV_STRIDE = 20;                      // q/k/v [64][20]
constexpr int Q_OFF = XT_OFF + kN * XT_STRIDE;      // 6208
constexpr int K_OFF = Q_OFF + kN * QKV_STRIDE;      // 7488
constexpr int V_OFF = K_OFF + kN * QKV_STRIDE;      // 8768
constexpr int BIAS_OFF = V_OFF + kN * QKV_STRIDE;   // 10048, 6*225 floats
constexpr int LAB_OFF = BIAS_OFF + 225 * kNH;       // 11398, 64 ints
constexpr int POOL = LAB_OFF + kN;                  // 11462 floats = 45848 B
}  // namespace

__global__ __launch_bounds__(256, 3) void swin_window_attn(
    const float* __restrict__ x,
    const float* __restrict__ bias_tab,
    const float* __restrict__ w_qkv,
    const float* __restrict__ b_qkv,
    const float* __restrict__ w_proj,
    const float* __restrict__ b_proj,
    float* __restrict__ out) {
  __shared__ __align__(16) float pool[POOL];
  float* xt = pool + XT_OFF;
  float* qS = pool + Q_OFF;
  float* kS = pool + K_OFF;
  float* vS = pool + V_OFF;
  float* biasS = pool + BIAS_OFF;
  int* labS = (int*)(pool + LAB_OFF);

  const int t = threadIdx.x;
  const int lane = t & 63;
  const int wv = __builtin_amdgcn_readfirstlane(t >> 6);  // wave id 0..3
  const int win = blockIdx.x;
  const int wh = win >> 6;
  const int wwi = win & 63;
  const int h0 = wh * kWS;
  const int w0 = wwi * kWS;

  // ---- Phase 0: gather window tile (raw-reshape + roll map), bias, labels --
  for (int e = t; e < kN * kC; e += 256) {
    const int n = e & 63;
    const int c = e >> 6;
    const int hh = h0 + (n >> 3);
    const int ww = w0 + (n & 7);
    const int idx = c * kHW + hh * kW + ww;     // flat idx in (C,H,W) view
    const int hp = idx / kWC;                   // decompose as (H,W,C) view
    const int rem = idx - hp * kWC;
    const int wp = rem / kC;
    const int cp = rem - wp * kC;
    int hs = hp + kShift; if (hs >= kH) hs -= kH;   // roll(-s): out[i]=in[i+s]
    int wsr = wp + kShift; if (wsr >= kW) wsr -= kW;
    xt[n * XT_STRIDE + c] = x[hs * kWC + wsr * kC + cp];
  }
  for (int e = t; e < 225 * kNH; e += 256) {    // biasS[h][225]
    const int hb = e / 225;
    const int i = e - hb * 225;
    biasS[e] = bias_tab[i * kNH + hb];
  }
  if (t < kN) {  // shift-mask region label per token (rolled-image coords)
    const int hh = h0 + (t >> 3);
    const int ww = w0 + (t & 7);
    const int lh = (hh < kH - kWS) ? 0 : (hh < kH - kShift ? 1 : 2);
    const int lw = (ww < kW - kWS) ? 0 : (ww < kW - kShift ? 1 : 2);
    labS[t] = lh * 3 + lw;
  }
  __syncthreads();

  // attn-phase (map B) identifiers
  const int cg = lane & 3;          // col-group within row
  const int gl = lane & ~3;         // wave-local base lane of my 4-lane group
  const int r = (wv << 4) + (lane >> 2);   // my score row (token)
  const int i1 = r >> 3, j1 = r & 7;

  float4 y0 = make_float4(0,0,0,0), y1 = y0, y2 = y0,
         y3 = y0, y4 = y0, y5 = y0;

#pragma unroll 1
  for (int h = 0; h < kNH; ++h) {
    // ---- QKV (map A): token = lane, dims wv*4..+3; weights wave-uniform ----
    const int row_q = h * 16 + (wv << 2);
    const float* __restrict__ wqp = w_qkv + row_q * kC;
    const float* __restrict__ wkp = w_qkv + (96 + row_q) * kC;
    const float* __restrict__ wvp = w_qkv + (192 + row_q) * kC;
    float aq[4], ak[4], av[4];
#pragma unroll
    for (int u = 0; u < 4; ++u) {
      aq[u] = b_qkv[row_q + u];
      ak[u] = b_qkv[96 + row_q + u];
      av[u] = b_qkv[192 + row_q + u];
    }
    const float* xrow = xt + lane * XT_STRIDE;
    for (int c = 0; c < kC; c += 4) {
      const float xv0 = xrow[c + 0];
      const float xv1 = xrow[c + 1];
      const float xv2 = xrow[c + 2];
      const float xv3 = xrow[c + 3];
#pragma unroll
      for (int u = 0; u < 4; ++u) {
        const float4 wq = *(const float4*)(wqp + u * kC + c);
        aq[u] += xv0 * wq.x + xv1 * wq.y + xv2 * wq.z + xv3 * wq.w;
        const float4 wk = *(const float4*)(wkp + u * kC + c);
        ak[u] += xv0 * wk.x + xv1 * wk.y + xv2 * wk.z + xv3 * wk.w;
        const float4 wvv = *(const float4*)(wvp + u * kC + c);
        av[u] += xv0 * wvv.x + xv1 * wvv.y + xv2 * wvv.z + xv3 * wvv.w;
      }
    }
    // q pre-scaled by hd^-0.5 = 0.25
    *(float4*)(qS + lane * QKV_STRIDE + (wv << 2)) =
        make_float4(aq[0] * 0.25f, aq[1] * 0.25f, aq[2] * 0.25f, aq[3] * 0.25f);
    *(float4*)(kS + lane * QKV_STRIDE + (wv << 2)) =
        make_float4(ak[0], ak[1], ak[2], ak[3]);
    *(float4*)(vS + lane * QKV_STRIDE + (wv << 2)) =
        make_float4(av[0], av[1], av[2], av[3]);
    __syncthreads();  // q/k/v visible

    // ---- scores (map B): row r, cols cg*16..+15 ----
    const float4 qv0 = *(const float4*)(qS + r * QKV_STRIDE + 0);
    const float4 qv1 = *(const float4*)(qS + r * QKV_STRIDE + 4);
    const float4 qv2 = *(const float4*)(qS + r * QKV_STRIDE + 8);
    const float4 qv3 = *(const float4*)(qS + r * QKV_STRIDE + 12);
    const int labn = labS[r];
    const float* biasH = biasS + h * 225;
    float sreg[16];
    float mx = -1e30f;
#pragma unroll
    for (int m = 0; m < 16; ++m) {
      const int col = (cg << 4) + m;
      const float4 k0 = *(const float4*)(kS + col * QKV_STRIDE + 0);
      const float4 k1 = *(const float4*)(kS + col * QKV_STRIDE + 4);
      const float4 k2 = *(const float4*)(kS + col * QKV_STRIDE + 8);
      const float4 k3 = *(const float4*)(kS + col * QKV_STRIDE + 12);
      float s = qv0.x * k0.x + qv0.y * k0.y + qv0.z * k0.z + qv0.w * k0.w
              + qv1.x * k1.x + qv1.y * k1.y + qv1.z * k1.z + qv1.w * k1.w
              + qv2.x * k2.x + qv2.y * k2.y + qv2.z * k2.z + qv2.w * k2.w
              + qv3.x * k3.x + qv3.y * k3.y + qv3.z * k3.z + qv3.w * k3.w;
      s += biasH[(i1 - (col >> 3) + 7) * 15 + (j1 - (col & 7) + 7)];
      s += (labS[col] != labn) ? -100.0f : 0.0f;
      sreg[m] = s;
      mx = fmaxf(mx, s);
    }
    // row softmax across the 4-lane group
    mx = fmaxf(mx, __shfl_xor(mx, 1));
    mx = fmaxf(mx, __shfl_xor(mx, 2));
    float sum = 0.f;
#pragma unroll
    for (int m = 0; m < 16; ++m) {
      const float e = __expf(sreg[m] - mx);
      sreg[m] = e;
      sum += e;
    }
    sum += __shfl_xor(sum, 1);
    sum += __shfl_xor(sum, 2);

    // ---- PV: p[r][m] lives on lane gl+(m>>4) at slot m&15 ----
    float a0 = 0.f, a1 = 0.f, a2 = 0.f, a3 = 0.f;
#pragma unroll
    for (int s2 = 0; s2 < 16; ++s2) {
#pragma unroll
      for (int g2 = 0; g2 < 4; ++g2) {
        const float p = __shfl(sreg[s2], gl + g2);
        const float4 vvv =
            *(const float4*)(vS + ((g2 << 4) + s2) * QKV_STRIDE + (cg << 2));
        a0 += p * vvv.x; a1 += p * vvv.y; a2 += p * vvv.z; a3 += p * vvv.w;
      }
    }
    const float inv = 1.0f / sum;
    const float4 yh = make_float4(a0 * inv, a1 * inv, a2 * inv, a3 * inv);
    if      (h == 0) y0 = yh;
    else if (h == 1) y1 = yh;
    else if (h == 2) y2 = yh;
    else if (h == 3) y3 = yh;
    else if (h == 4) y4 = yh;
    else             y5 = yh;
    __syncthreads();  // vS/kS/qS readers done before next head's writes
  }

  // ---- stage y into the (now dead) xt region: yS[r][h*16 + cg*4 + u] ----
  {
    float* yw = xt + r * XT_STRIDE + (cg << 2);
    yw[0]  = y0.x; yw[1]  = y0.y; yw[2]  = y0.z; yw[3]  = y0.w;
    yw[16] = y1.x; yw[17] = y1.y; yw[18] = y1.z; yw[19] = y1.w;
    yw[32] = y2.x; yw[33] = y2.y; yw[34] = y2.z; yw[35] = y2.w;
    yw[48] = y3.x; yw[49] = y3.y; yw[50] = y3.z; yw[51] = y3.w;
    yw[64] = y4.x; yw[65] = y4.y; yw[66] = y4.z; yw[67] = y4.w;
    yw[80] = y5.x; yw[81] = y5.y; yw[82] = y5.z; yw[83] = y5.w;
  }
  __syncthreads();

  // ---- proj (map A): token = lane, oc = wv*24..+23; weights wave-uniform ---
  const int oc0 = wv * 24;
  const int hh = h0 + (lane >> 3);
  const int ww = w0 + (lane & 7);
  const float* yrow = xt + lane * XT_STRIDE;
  float acc[24];
#pragma unroll
  for (int j = 0; j < 24; ++j) acc[j] = b_proj[oc0 + j];
  for (int c = 0; c < kC; c += 2) {
    const float yv0 = yrow[c];
    const float yv1 = yrow[c + 1];
#pragma unroll
    for (int j = 0; j < 24; ++j) {
      const float2 wp2 = *(const float2*)(w_proj + (oc0 + j) * kC + c);
      acc[j] += yv0 * wp2.x + yv1 * wp2.y;
    }
  }
#pragma unroll
  for (int j = 0; j < 24; ++j)
    out[(oc0 + j) * kHW + hh * kW + ww] = acc[j];
}

extern "C" void kernel_launch(void* const* d_in, const int* in_sizes, int n_in,
                              void* d_out, int out_size, void* d_ws, size_t ws_size,
                              hipStream_t stream) {
  const float* x  = (const float*)d_in[0];
  const float* bt = (const float*)d_in[1];
  const float* wq = (const float*)d_in[2];
  const float* bq = (const float*)d_in[3];
  const float* wp = (const float*)d_in[4];
  const float* bp = (const float*)d_in[5];
  // d_in[6..8] = window_size/num_heads/shift_size scalars: compile-time here.
  float* out = (float*)d_out;
  swin_window_attn<<<dim3(64 * 64), dim3(256), 0, stream>>>(x, bt, wq, bq, wp, bp, out);
}

// Round 3
// 923.088 us; speedup vs baseline: 3.8448x; 1.0048x over previous
//
#include <hip/hip_runtime.h>

// Swin shifted-window attention, B=1, C=96, H=W=512, ws=8, heads=6, shift=4.
// All inputs/outputs fp32.
//
// v3b: LDS-pipe diet + occupancy (v3 with ds_swizzle ICE fix).
//  - score col map col=4m+cg  -> k-reads bank-conflict-free (was 4-way)
//  - mask via per-thread 64-bit bitmap (edge blocks only) -> labS gone
//  - bias read from L2 (16 prefetched regs/head)          -> biasS gone
//  - pool 39.3KB -> 4 blocks/CU (16 waves) via __launch_bounds__(256,4)
//  - PV broadcast via ds_swizzle with LITERAL offsets (0x1C/0x3C/0x5C/0x7C)

namespace {
constexpr int kH = 512, kW = 512, kC = 96;
constexpr int kWS = 8, kN = 64, kNH = 6;
constexpr int kShift = 4;
constexpr int kHW = kH * kW;   // 262144
constexpr int kWC = kW * kC;   // 49152

constexpr int XT_STRIDE = 97;                       // xt / yS [64][97]
constexpr int XT_OFF = 0;
constexpr int QKV_STRIDE = 20;                      // q/k/v [64][20]
constexpr int Q_OFF = XT_OFF + kN * XT_STRIDE;      // 6208
constexpr int K_OFF = Q_OFF + kN * QKV_STRIDE;      // 7488
constexpr int V_OFF = K_OFF + kN * QKV_STRIDE;      // 8768
constexpr int POOL = V_OFF + kN * QKV_STRIDE;       // 10048 floats = 40192 B
}  // namespace

__global__ __launch_bounds__(256, 4) void swin_window_attn(
    const float* __restrict__ x,
    const float* __restrict__ bias_tab,
    const float* __restrict__ w_qkv,
    const float* __restrict__ b_qkv,
    const float* __restrict__ w_proj,
    const float* __restrict__ b_proj,
    float* __restrict__ out) {
  __shared__ __align__(16) float pool[POOL];
  float* xt = pool + XT_OFF;
  float* qS = pool + Q_OFF;
  float* kS = pool + K_OFF;
  float* vS = pool + V_OFF;

  const int t = threadIdx.x;
  const int lane = t & 63;
  const int wv = __builtin_amdgcn_readfirstlane(t >> 6);  // wave id 0..3
  const int win = blockIdx.x;
  const int wh = win >> 6;
  const int wwi = win & 63;
  const int h0 = wh * kWS;
  const int w0 = wwi * kWS;

  // ---- Phase 0: gather window tile (raw-reshape + roll map) ----
  for (int e = t; e < kN * kC; e += 256) {
    const int n = e & 63;
    const int c = e >> 6;
    const int hh = h0 + (n >> 3);
    const int ww = w0 + (n & 7);
    const int idx = c * kHW + hh * kW + ww;     // flat idx in (C,H,W) view
    const int hp = idx / kWC;                   // decompose as (H,W,C) view
    const int rem = idx - hp * kWC;
    const int wp = rem / kC;
    const int cp = rem - wp * kC;
    int hs = hp + kShift; if (hs >= kH) hs -= kH;   // roll(-s): out[i]=in[i+s]
    int wsr = wp + kShift; if (wsr >= kW) wsr -= kW;
    xt[n * XT_STRIDE + c] = x[hs * kWC + wsr * kC + cp];
  }

  // attn-phase (map B) identifiers
  const int cg = lane & 3;          // col-group within row: cols 4m+cg
  const int r = (wv << 4) + (lane >> 2);   // my score row (token)
  const int i1 = r >> 3, j1 = r & 7;

  // ---- shift-mask bitmap for my row (edge blocks only; wave-uniform) ----
  unsigned mlo = 0, mhi = 0;
  if (wh == 63 || wwi == 63) {
    const int rh = h0 + (r >> 3), rw = w0 + (r & 7);
    const int labr = ((rh >= kH - kWS) + (rh >= kH - kShift)) * 3 +
                     (rw >= kW - kWS) + (rw >= kW - kShift);
    for (int m2 = 0; m2 < 64; ++m2) {
      const int ch = h0 + (m2 >> 3), cw2 = w0 + (m2 & 7);
      const int labc = ((ch >= kH - kWS) + (ch >= kH - kShift)) * 3 +
                       (cw2 >= kW - kWS) + (cw2 >= kW - kShift);
      const unsigned bit = (labc != labr) ? 1u : 0u;
      if (m2 < 32) mlo |= bit << m2; else mhi |= bit << (m2 - 32);
    }
  }
  // bit for col=4m+cg is ((m<8?umlo:umhi) >> 4*(m&7)) & 1
  const unsigned umlo = mlo >> cg, umhi = mhi >> cg;

  __syncthreads();

  float4 y0 = make_float4(0, 0, 0, 0), y1 = y0, y2 = y0,
         y3 = y0, y4 = y0, y5 = y0;

#pragma unroll 1
  for (int h = 0; h < kNH; ++h) {
    if (h) __syncthreads();  // prev head's qS/kS/vS readers done

    // ---- QKV (map A): token = lane, dims wv*4..+3; weights wave-uniform ----
    const int row_q = h * 16 + (wv << 2);
    const float* __restrict__ wqp = w_qkv + row_q * kC;
    const float* __restrict__ wkp = w_qkv + (96 + row_q) * kC;
    const float* __restrict__ wvp = w_qkv + (192 + row_q) * kC;
    float aq[4], ak[4], av[4];
#pragma unroll
    for (int u = 0; u < 4; ++u) {
      aq[u] = b_qkv[row_q + u];
      ak[u] = b_qkv[96 + row_q + u];
      av[u] = b_qkv[192 + row_q + u];
    }
    const float* xrow = xt + lane * XT_STRIDE;
    for (int c = 0; c < kC; c += 4) {
      const float xv0 = xrow[c + 0];
      const float xv1 = xrow[c + 1];
      const float xv2 = xrow[c + 2];
      const float xv3 = xrow[c + 3];
#pragma unroll
      for (int u = 0; u < 4; ++u) {
        const float4 wq = *(const float4*)(wqp + u * kC + c);
        aq[u] += xv0 * wq.x + xv1 * wq.y + xv2 * wq.z + xv3 * wq.w;
        const float4 wk = *(const float4*)(wkp + u * kC + c);
        ak[u] += xv0 * wk.x + xv1 * wk.y + xv2 * wk.z + xv3 * wk.w;
        const float4 wvv = *(const float4*)(wvp + u * kC + c);
        av[u] += xv0 * wvv.x + xv1 * wvv.y + xv2 * wvv.z + xv3 * wvv.w;
      }
    }
    // q pre-scaled by hd^-0.5 = 0.25
    *(float4*)(qS + lane * QKV_STRIDE + (wv << 2)) =
        make_float4(aq[0] * 0.25f, aq[1] * 0.25f, aq[2] * 0.25f, aq[3] * 0.25f);
    *(float4*)(kS + lane * QKV_STRIDE + (wv << 2)) =
        make_float4(ak[0], ak[1], ak[2], ak[3]);
    *(float4*)(vS + lane * QKV_STRIDE + (wv << 2)) =
        make_float4(av[0], av[1], av[2], av[3]);
    __syncthreads();  // q/k/v visible

    // ---- bias prefetch from L2 into regs (VMEM pipe, not LDS) ----
    float bv[16];
#pragma unroll
    for (int m = 0; m < 16; ++m) {
      const int col = (m << 2) | cg;
      const int bidx = (i1 - (col >> 3) + 7) * 15 + (j1 - (col & 7) + 7);
      bv[m] = bias_tab[bidx * kNH + h];
    }

    // ---- scores (map B): row r, cols 4m+cg (bank-conflict-free k reads) ----
    const float4 qv0 = *(const float4*)(qS + r * QKV_STRIDE + 0);
    const float4 qv1 = *(const float4*)(qS + r * QKV_STRIDE + 4);
    const float4 qv2 = *(const float4*)(qS + r * QKV_STRIDE + 8);
    const float4 qv3 = *(const float4*)(qS + r * QKV_STRIDE + 12);
    float sreg[16];
    float mx = -1e30f;
#pragma unroll
    for (int m = 0; m < 16; ++m) {
      const int col = (m << 2) | cg;
      const float4 k0 = *(const float4*)(kS + col * QKV_STRIDE + 0);
      const float4 k1 = *(const float4*)(kS + col * QKV_STRIDE + 4);
      const float4 k2 = *(const float4*)(kS + col * QKV_STRIDE + 8);
      const float4 k3 = *(const float4*)(kS + col * QKV_STRIDE + 12);
      float s = qv0.x * k0.x + qv0.y * k0.y + qv0.z * k0.z + qv0.w * k0.w
              + qv1.x * k1.x + qv1.y * k1.y + qv1.z * k1.z + qv1.w * k1.w
              + qv2.x * k2.x + qv2.y * k2.y + qv2.z * k2.z + qv2.w * k2.w
              + qv3.x * k3.x + qv3.y * k3.y + qv3.z * k3.z + qv3.w * k3.w;
      s += bv[m];
      const unsigned um = (m < 8) ? umlo : umhi;
      s += ((um >> ((m & 7) << 2)) & 1u) ? -100.0f : 0.0f;
      sreg[m] = s;
      mx = fmaxf(mx, s);
    }
    // row softmax across the 4-lane group
    mx = fmaxf(mx, __shfl_xor(mx, 1));
    mx = fmaxf(mx, __shfl_xor(mx, 2));
    float sum = 0.f;
#pragma unroll
    for (int m = 0; m < 16; ++m) {
      const float e = __expf(sreg[m] - mx);
      sreg[m] = e;
      sum += e;
    }
    sum += __shfl_xor(sum, 1);
    sum += __shfl_xor(sum, 2);

    // ---- PV: p[r][4*s2+g2] lives on group lane g2 at slot s2 ----
    // broadcast from group lane g2: lane' = (lane & 0x1C) | g2
    // BitMode swizzle offset = (xor<<10)|(or<<5)|and with and=0x1C, or=g2.
    float a0 = 0.f, a1 = 0.f, a2 = 0.f, a3 = 0.f;
#pragma unroll
    for (int s2 = 0; s2 < 16; ++s2) {
      const int pbits = __float_as_int(sreg[s2]);
      float pb[4];
      pb[0] = __int_as_float(__builtin_amdgcn_ds_swizzle(pbits, 0x001C));
      pb[1] = __int_as_float(__builtin_amdgcn_ds_swizzle(pbits, 0x003C));
      pb[2] = __int_as_float(__builtin_amdgcn_ds_swizzle(pbits, 0x005C));
      pb[3] = __int_as_float(__builtin_amdgcn_ds_swizzle(pbits, 0x007C));
#pragma unroll
      for (int g2 = 0; g2 < 4; ++g2) {
        const float4 vvv =
            *(const float4*)(vS + ((s2 << 2) | g2) * QKV_STRIDE + (cg << 2));
        a0 += pb[g2] * vvv.x; a1 += pb[g2] * vvv.y;
        a2 += pb[g2] * vvv.z; a3 += pb[g2] * vvv.w;
      }
    }
    const float inv = 1.0f / sum;
    const float4 yh = make_float4(a0 * inv, a1 * inv, a2 * inv, a3 * inv);
    if      (h == 0) y0 = yh;
    else if (h == 1) y1 = yh;
    else if (h == 2) y2 = yh;
    else if (h == 3) y3 = yh;
    else if (h == 4) y4 = yh;
    else             y5 = yh;
  }

  // ---- stage y into the (now dead) xt region: yS[r][h*16 + cg*4 + u] ----
  // xt reads all happened before head-5's publish barrier; safe to overwrite.
  {
    float* yw = xt + r * XT_STRIDE + (cg << 2);
    yw[0]  = y0.x; yw[1]  = y0.y; yw[2]  = y0.z; yw[3]  = y0.w;
    yw[16] = y1.x; yw[17] = y1.y; yw[18] = y1.z; yw[19] = y1.w;
    yw[32] = y2.x; yw[33] = y2.y; yw[34] = y2.z; yw[35] = y2.w;
    yw[48] = y3.x; yw[49] = y3.y; yw[50] = y3.z; yw[51] = y3.w;
    yw[64] = y4.x; yw[65] = y4.y; yw[66] = y4.z; yw[67] = y4.w;
    yw[80] = y5.x; yw[81] = y5.y; yw[82] = y5.z; yw[83] = y5.w;
  }
  __syncthreads();

  // ---- proj (map A): token = lane, oc = wv*24..+23; weights wave-uniform ---
  const int oc0 = wv * 24;
  const int hh = h0 + (lane >> 3);
  const int ww = w0 + (lane & 7);
  const float* yrow = xt + lane * XT_STRIDE;
  float acc[24];
#pragma unroll
  for (int j = 0; j < 24; ++j) acc[j] = b_proj[oc0 + j];
  for (int c = 0; c < kC; c += 2) {
    const float yv0 = yrow[c];
    const float yv1 = yrow[c + 1];
#pragma unroll
    for (int j = 0; j < 24; ++j) {
      const float2 wp2 = *(const float2*)(w_proj + (oc0 + j) * kC + c);
      acc[j] += yv0 * wp2.x + yv1 * wp2.y;
    }
  }
#pragma unroll
  for (int j = 0; j < 24; ++j)
    out[(oc0 + j) * kHW + hh * kW + ww] = acc[j];
}

extern "C" void kernel_launch(void* const* d_in, const int* in_sizes, int n_in,
                              void* d_out, int out_size, void* d_ws, size_t ws_size,
                              hipStream_t stream) {
  const float* x  = (const float*)d_in[0];
  const float* bt = (const float*)d_in[1];
  const float* wq = (const float*)d_in[2];
  const float* bq = (const float*)d_in[3];
  const float* wp = (const float*)d_in[4];
  const float* bp = (const float*)d_in[5];
  // d_in[6..8] = window_size/num_heads/shift_size scalars: compile-time here.
  float* out = (float*)d_out;
  swin_window_attn<<<dim3(64 * 64), dim3(256), 0, stream>>>(x, bt, wq, bq, wp, bp, out);
}